// Round 13
// baseline (47.003 us; speedup 1.0000x reference)
//
#include <hip/hip_runtime.h>
#include <math.h>

#define NB   4
#define NH   16
#define NT   4096
#define ND   64
#define NP   256
#define NREG 64
#define RPOS 4

// log2(10000) / 32  (inv_freq[j] = 10000^(-2j/64))
#define INVF_LOG2 0.4152410118609203f
// 0.125 (1/sqrt(64)) * log2(e): fold into q so score feeds exp2 directly
#define QSCALE 0.18033688011112042f

typedef float vfloat4 __attribute__((ext_vector_type(4)));

// One kernel. Block = 4 waves = 4 regions; wave = one (b,h,region), all 4 pools.
// Bounds via sampled lower_bound (2 ballot rounds). Depth-2 register prefetch,
// pinned with sched_barrier so the compiler cannot sink the loads to their use
// (R5/R10/R12 all compiled to VGPR=64 => pipeline was being folded away).
// Grid = 4 blocks/CU = 4 waves/SIMD, so VGPR up to 128 costs no occupancy.
__global__ __launch_bounds__(256, 4) void lca_kernel(
    const float* __restrict__ q,
    const float* __restrict__ k,
    const float* __restrict__ v,
    const int*   __restrict__ regions,
    float*       __restrict__ out)
{
    const int tid  = threadIdx.x;
    const int wave = tid >> 6;
    const int lane = tid & 63;
    const int grp  = lane >> 3;   // 0..7 : token within 8-token iter
    const int li   = lane & 7;    // 0..7 : dim chunk
    const int dlo  = li << 2;     // low dims dlo..dlo+3 ; high +32 (in-lane RoPE pair)

    const int blk = blockIdx.x;   // ((b*NH)+h)*16 + rg
    const int rg  = blk & 15;
    const int h   = (blk >> 4) & (NH - 1);
    const int b   = blk >> 8;
    const int ri  = (rg << 2) + wave;  // region index 0..63 (value ri+1)
    const int p0  = ri << 2;           // first of the region's 4 pools

    const size_t bh = (size_t)(b * NH + h);
    const float* kb = k + bh * (size_t)(NT * ND);
    const float* vb = v + bh * (size_t)(NT * ND);
    const float* qb = q + (bh * NP + p0) * ND;
    const int*   rb = regions + b * NT;

    // ---- issue independent loads up front: region samples + q (4 pools) ----
    const int samp = rb[lane << 6];    // lane j samples regions[b][64*j]

    float qs[4][8];
    #pragma unroll
    for (int p = 0; p < 4; ++p) {
        const float4 qa = *(const float4*)(qb + p * ND + dlo);
        const float4 qc = *(const float4*)(qb + p * ND + 32 + dlo);
        qs[p][0] = qa.x * QSCALE; qs[p][1] = qa.y * QSCALE;
        qs[p][2] = qa.z * QSCALE; qs[p][3] = qa.w * QSCALE;
        qs[p][4] = qc.x * QSCALE; qs[p][5] = qc.y * QSCALE;
        qs[p][6] = qc.z * QSCALE; qs[p][7] = qc.w * QSCALE;
    }

    // ---- sampled lower_bound for targets ri+1 (s) and ri+2 (e) ----
    // c = #samples < v  ->  bound in (64(c-1), 64c]; window read + ballot = exact.
    const int c1  = __popcll(__ballot(samp < ri + 1));
    const int c2  = __popcll(__ballot(samp < ri + 2));
    const int st1 = (c1 == 0) ? 0 : ((c1 - 1) << 6) + 1;
    const int st2 = (c2 == 0) ? 0 : ((c2 - 1) << 6) + 1;
    const int i1  = st1 + lane;
    const int i2  = st2 + lane;
    const int w1  = (i1 < NT) ? rb[i1] : 0x7fffffff;
    const int w2  = (i2 < NT) ? rb[i2] : 0x7fffffff;
    const int s   = st1 + __popcll(__ballot(w1 < ri + 1));
    const int e   = st2 + __popcll(__ballot(w2 < ri + 2));
    const int cnt = e - s;

    float l4[4] = {0.f, 0.f, 0.f, 0.f};
    float acc[4][8];
    #pragma unroll
    for (int p = 0; p < 4; ++p)
        #pragma unroll
        for (int i = 0; i < 8; ++i) acc[p][i] = 0.f;

    if (cnt > 0) {
        float frq[4];
        #pragma unroll
        for (int i = 0; i < 4; ++i)
            frq[i] = exp2f(-INVF_LOG2 * (float)(dlo + i));

        const int iters = (cnt + 7) >> 3;

        // prologue: load iterations 0 and 1 (clamped; dups harmless)
        const int tA = min(s + grp, e - 1);
        const int tB = min(s + 8 + grp, e - 1);
        const float* pA = kb + (size_t)tA * ND;
        const float* pB = kb + (size_t)tB * ND;
        const float* qA = vb + (size_t)tA * ND;
        const float* qB = vb + (size_t)tB * ND;
        vfloat4 kc0 = *(const vfloat4*)(pA + dlo);
        vfloat4 kc1 = *(const vfloat4*)(pA + 32 + dlo);
        vfloat4 vc0 = *(const vfloat4*)(qA + dlo);
        vfloat4 vc1 = *(const vfloat4*)(qA + 32 + dlo);
        vfloat4 kn0 = *(const vfloat4*)(pB + dlo);
        vfloat4 kn1 = *(const vfloat4*)(pB + 32 + dlo);
        vfloat4 vn0 = *(const vfloat4*)(qB + dlo);
        vfloat4 vn1 = *(const vfloat4*)(qB + 32 + dlo);

        #pragma unroll 2
        for (int it = 0; it < iters; ++it) {
            // prefetch iteration it+2 (depth 2)
            const int tp = min(s + ((it + 2) << 3) + grp, e - 1);
            const float* kp = kb + (size_t)tp * ND;
            const float* vp = vb + (size_t)tp * ND;
            const vfloat4 kp0 = *(const vfloat4*)(kp + dlo);
            const vfloat4 kp1 = *(const vfloat4*)(kp + 32 + dlo);
            const vfloat4 vp0 = *(const vfloat4*)(vp + dlo);
            const vfloat4 vp1 = *(const vfloat4*)(vp + 32 + dlo);
            // pin: loads may not sink below, compute may not hoist above.
            // (no waitcnt here -- waits happen at first register READ, 2 iters later)
            __builtin_amdgcn_sched_barrier(0);

            const int   off   = (it << 3) + grp;
            const bool  valid = off < cnt;
            const float pos   = (float)(off + RPOS);   // unclamped: invalid lanes get w=0

            const float klo[4] = {kc0.x, kc0.y, kc0.z, kc0.w};
            const float khi[4] = {kc1.x, kc1.y, kc1.z, kc1.w};
            float pd0 = 0.f, pd1 = 0.f, pd2 = 0.f, pd3 = 0.f;
            #pragma unroll
            for (int i = 0; i < 4; ++i) {
                float sa, ca;
                __sincosf(pos * frq[i], &sa, &ca);
                const float rlo = klo[i] * ca - khi[i] * sa;
                const float rhi = khi[i] * ca + klo[i] * sa;
                pd0 = fmaf(rlo, qs[0][i], fmaf(rhi, qs[0][i + 4], pd0));
                pd1 = fmaf(rlo, qs[1][i], fmaf(rhi, qs[1][i + 4], pd1));
                pd2 = fmaf(rlo, qs[2][i], fmaf(rhi, qs[2][i + 4], pd2));
                pd3 = fmaf(rlo, qs[3][i], fmaf(rhi, qs[3][i + 4], pd3));
            }
            // reduce over the 8 dim-chunk lanes (bits 0..2)
            #pragma unroll
            for (int m = 1; m <= 4; m <<= 1) {
                pd0 += __shfl_xor(pd0, m);
                pd1 += __shfl_xor(pd1, m);
                pd2 += __shfl_xor(pd2, m);
                pd3 += __shfl_xor(pd3, m);
            }
            const float w0 = valid ? exp2f(pd0) : 0.f;
            const float w1v = valid ? exp2f(pd1) : 0.f;
            const float w2v = valid ? exp2f(pd2) : 0.f;
            const float w3v = valid ? exp2f(pd3) : 0.f;
            l4[0] += w0; l4[1] += w1v; l4[2] += w2v; l4[3] += w3v;
            const float vx[8] = {vc0.x, vc0.y, vc0.z, vc0.w, vc1.x, vc1.y, vc1.z, vc1.w};
            #pragma unroll
            for (int i = 0; i < 8; ++i) {
                acc[0][i] = fmaf(w0,  vx[i], acc[0][i]);
                acc[1][i] = fmaf(w1v, vx[i], acc[1][i]);
                acc[2][i] = fmaf(w2v, vx[i], acc[2][i]);
                acc[3][i] = fmaf(w3v, vx[i], acc[3][i]);
            }
            // rotate buffers: cur <- next <- prefetch (renamed away by unroll-2)
            kc0 = kn0; kc1 = kn1; vc0 = vn0; vc1 = vn1;
            kn0 = kp0; kn1 = kp1; vn0 = vp0; vn1 = vp1;
        }
    } else {
        // empty region: softmax over all -1e30 -> uniform mean of v over all T
        for (int t = grp; t < NT; t += 8) {
            const float* vp = vb + (size_t)t * ND;
            const float4 va = *(const float4*)(vp + dlo);
            const float4 vc = *(const float4*)(vp + 32 + dlo);
            acc[0][0] += va.x; acc[0][1] += va.y; acc[0][2] += va.z; acc[0][3] += va.w;
            acc[0][4] += vc.x; acc[0][5] += vc.y; acc[0][6] += vc.z; acc[0][7] += vc.w;
        }
        #pragma unroll
        for (int p = 1; p < 4; ++p)
            #pragma unroll
            for (int i = 0; i < 8; ++i) acc[p][i] = acc[0][i];
        // butterfly below sums 8 groups: pre-divide so l totals NT
        l4[0] = l4[1] = l4[2] = l4[3] = (float)NT * 0.125f;
    }

    // butterfly-reduce the 8 token-groups (bits 3..5); all lanes end with totals
    #pragma unroll
    for (int m = 8; m <= 32; m <<= 1) {
        #pragma unroll
        for (int p = 0; p < 4; ++p) {
            l4[p] += __shfl_xor(l4[p], m);
            #pragma unroll
            for (int i = 0; i < 8; ++i) acc[p][i] += __shfl_xor(acc[p][i], m);
        }
    }

    // groups 0..3 write pool p0+grp; non-temporal (out never re-read)
    #pragma unroll
    for (int p = 0; p < 4; ++p) {
        if (grp == p) {
            const float inv = 1.f / l4[p];
            float* op = out + (bh * NP + p0 + p) * ND;
            const vfloat4 o0 = {acc[p][0] * inv, acc[p][1] * inv,
                                acc[p][2] * inv, acc[p][3] * inv};
            const vfloat4 o1 = {acc[p][4] * inv, acc[p][5] * inv,
                                acc[p][6] * inv, acc[p][7] * inv};
            __builtin_nontemporal_store(o0, (vfloat4*)(op + dlo));
            __builtin_nontemporal_store(o1, (vfloat4*)(op + 32 + dlo));
        }
    }
}

extern "C" void kernel_launch(void* const* d_in, const int* in_sizes, int n_in,
                              void* d_out, int out_size, void* d_ws, size_t ws_size,
                              hipStream_t stream) {
    (void)in_sizes; (void)n_in; (void)d_ws; (void)ws_size; (void)out_size;
    const float* q       = (const float*)d_in[0];
    const float* k       = (const float*)d_in[1];
    const float* v       = (const float*)d_in[2];
    const int*   regions = (const int*)d_in[3];
    // d_in[4] t_mask, d_in[5] n_mask all-true; d_in[6] max_n == 64
    float* out = (float*)d_out;

    lca_kernel<<<dim3(NB * NH * (NREG / 4)), 256, 0, stream>>>(q, k, v, regions, out);
}

// Round 14
// 30.818 us; speedup vs baseline: 1.5252x; 1.5252x over previous
//
#include <hip/hip_runtime.h>
#include <math.h>

#define NB   4
#define NH   16
#define NT   4096
#define ND   64
#define NP   256
#define NREG 64
#define RPOS 4

// log2(10000) / 32  (inv_freq[j] = 10000^(-2j/64))
#define INVF_LOG2 0.4152410118609203f
// 0.125 (1/sqrt(64)) * log2(e): fold into q so score feeds exp2 directly
#define QSCALE 0.18033688011112042f

typedef float vfloat4 __attribute__((ext_vector_type(4)));

// One kernel. Block = 4 waves = 4 regions; wave = one (b,h,region), all 4 pools.
// Bounds via sampled lower_bound (2 ballot rounds). Depth-2 register prefetch.
// amdgpu_waves_per_eu(2,4): grid supplies only 4 waves/EU, so cap the
// scheduler's occupancy target there -> it may spend up to 256 VGPR keeping
// the prefetch in flight instead of sinking loads to their use (R12: VGPR=64).
__global__ __launch_bounds__(256)
__attribute__((amdgpu_waves_per_eu(2, 4)))
void lca_kernel(
    const float* __restrict__ q,
    const float* __restrict__ k,
    const float* __restrict__ v,
    const int*   __restrict__ regions,
    float*       __restrict__ out)
{
    const int tid  = threadIdx.x;
    const int wave = tid >> 6;
    const int lane = tid & 63;
    const int grp  = lane >> 3;   // 0..7 : token within 8-token iter
    const int li   = lane & 7;    // 0..7 : dim chunk
    const int dlo  = li << 2;     // low dims dlo..dlo+3 ; high +32 (in-lane RoPE pair)

    const int blk = blockIdx.x;   // ((b*NH)+h)*16 + rg
    const int rg  = blk & 15;
    const int h   = (blk >> 4) & (NH - 1);
    const int b   = blk >> 8;
    const int ri  = (rg << 2) + wave;  // region index 0..63 (value ri+1)
    const int p0  = ri << 2;           // first of the region's 4 pools

    const size_t bh = (size_t)(b * NH + h);
    const float* kb = k + bh * (size_t)(NT * ND);
    const float* vb = v + bh * (size_t)(NT * ND);
    const float* qb = q + (bh * NP + p0) * ND;
    const int*   rb = regions + b * NT;

    // ---- issue independent loads up front: region samples + q (4 pools) ----
    const int samp = rb[lane << 6];    // lane j samples regions[b][64*j]

    float qs[4][8];
    #pragma unroll
    for (int p = 0; p < 4; ++p) {
        const float4 qa = *(const float4*)(qb + p * ND + dlo);
        const float4 qc = *(const float4*)(qb + p * ND + 32 + dlo);
        qs[p][0] = qa.x * QSCALE; qs[p][1] = qa.y * QSCALE;
        qs[p][2] = qa.z * QSCALE; qs[p][3] = qa.w * QSCALE;
        qs[p][4] = qc.x * QSCALE; qs[p][5] = qc.y * QSCALE;
        qs[p][6] = qc.z * QSCALE; qs[p][7] = qc.w * QSCALE;
    }

    // ---- sampled lower_bound for targets ri+1 (s) and ri+2 (e) ----
    // c = #samples < v  ->  bound in (64(c-1), 64c]; window read + ballot = exact.
    const int c1  = __popcll(__ballot(samp < ri + 1));
    const int c2  = __popcll(__ballot(samp < ri + 2));
    const int st1 = (c1 == 0) ? 0 : ((c1 - 1) << 6) + 1;
    const int st2 = (c2 == 0) ? 0 : ((c2 - 1) << 6) + 1;
    const int i1  = st1 + lane;
    const int i2  = st2 + lane;
    const int w1  = (i1 < NT) ? rb[i1] : 0x7fffffff;
    const int w2  = (i2 < NT) ? rb[i2] : 0x7fffffff;
    const int s   = st1 + __popcll(__ballot(w1 < ri + 1));
    const int e   = st2 + __popcll(__ballot(w2 < ri + 2));
    const int cnt = e - s;

    float l4[4] = {0.f, 0.f, 0.f, 0.f};
    float acc[4][8];
    #pragma unroll
    for (int p = 0; p < 4; ++p)
        #pragma unroll
        for (int i = 0; i < 8; ++i) acc[p][i] = 0.f;

    if (cnt > 0) {
        float frq[4];
        #pragma unroll
        for (int i = 0; i < 4; ++i)
            frq[i] = exp2f(-INVF_LOG2 * (float)(dlo + i));

        const int iters = (cnt + 7) >> 3;

        // prologue: load iterations 0 and 1 (clamped; dups harmless)
        const int tA = min(s + grp, e - 1);
        const int tB = min(s + 8 + grp, e - 1);
        const float* pA = kb + (size_t)tA * ND;
        const float* pB = kb + (size_t)tB * ND;
        const float* qA = vb + (size_t)tA * ND;
        const float* qB = vb + (size_t)tB * ND;
        vfloat4 kc0 = *(const vfloat4*)(pA + dlo);
        vfloat4 kc1 = *(const vfloat4*)(pA + 32 + dlo);
        vfloat4 vc0 = *(const vfloat4*)(qA + dlo);
        vfloat4 vc1 = *(const vfloat4*)(qA + 32 + dlo);
        vfloat4 kn0 = *(const vfloat4*)(pB + dlo);
        vfloat4 kn1 = *(const vfloat4*)(pB + 32 + dlo);
        vfloat4 vn0 = *(const vfloat4*)(qB + dlo);
        vfloat4 vn1 = *(const vfloat4*)(qB + 32 + dlo);

        #pragma unroll 2
        for (int it = 0; it < iters; ++it) {
            // prefetch iteration it+2 (depth 2)
            const int tp = min(s + ((it + 2) << 3) + grp, e - 1);
            const float* kp = kb + (size_t)tp * ND;
            const float* vp = vb + (size_t)tp * ND;
            const vfloat4 kp0 = *(const vfloat4*)(kp + dlo);
            const vfloat4 kp1 = *(const vfloat4*)(kp + 32 + dlo);
            const vfloat4 vp0 = *(const vfloat4*)(vp + dlo);
            const vfloat4 vp1 = *(const vfloat4*)(vp + 32 + dlo);

            const int   off   = (it << 3) + grp;
            const bool  valid = off < cnt;
            const float pos   = (float)(off + RPOS);   // unclamped: invalid lanes get w=0

            const float klo[4] = {kc0.x, kc0.y, kc0.z, kc0.w};
            const float khi[4] = {kc1.x, kc1.y, kc1.z, kc1.w};
            float pd0 = 0.f, pd1 = 0.f, pd2 = 0.f, pd3 = 0.f;
            #pragma unroll
            for (int i = 0; i < 4; ++i) {
                float sa, ca;
                __sincosf(pos * frq[i], &sa, &ca);
                const float rlo = klo[i] * ca - khi[i] * sa;
                const float rhi = khi[i] * ca + klo[i] * sa;
                pd0 = fmaf(rlo, qs[0][i], fmaf(rhi, qs[0][i + 4], pd0));
                pd1 = fmaf(rlo, qs[1][i], fmaf(rhi, qs[1][i + 4], pd1));
                pd2 = fmaf(rlo, qs[2][i], fmaf(rhi, qs[2][i + 4], pd2));
                pd3 = fmaf(rlo, qs[3][i], fmaf(rhi, qs[3][i + 4], pd3));
            }
            // reduce over the 8 dim-chunk lanes (bits 0..2)
            #pragma unroll
            for (int m = 1; m <= 4; m <<= 1) {
                pd0 += __shfl_xor(pd0, m);
                pd1 += __shfl_xor(pd1, m);
                pd2 += __shfl_xor(pd2, m);
                pd3 += __shfl_xor(pd3, m);
            }
            const float w0 = valid ? exp2f(pd0) : 0.f;
            const float w1v = valid ? exp2f(pd1) : 0.f;
            const float w2v = valid ? exp2f(pd2) : 0.f;
            const float w3v = valid ? exp2f(pd3) : 0.f;
            l4[0] += w0; l4[1] += w1v; l4[2] += w2v; l4[3] += w3v;
            const float vx[8] = {vc0.x, vc0.y, vc0.z, vc0.w, vc1.x, vc1.y, vc1.z, vc1.w};
            #pragma unroll
            for (int i = 0; i < 8; ++i) {
                acc[0][i] = fmaf(w0,  vx[i], acc[0][i]);
                acc[1][i] = fmaf(w1v, vx[i], acc[1][i]);
                acc[2][i] = fmaf(w2v, vx[i], acc[2][i]);
                acc[3][i] = fmaf(w3v, vx[i], acc[3][i]);
            }
            // rotate buffers: cur <- next <- prefetch (renamed away by unroll-2)
            kc0 = kn0; kc1 = kn1; vc0 = vn0; vc1 = vn1;
            kn0 = kp0; kn1 = kp1; vn0 = vp0; vn1 = vp1;
        }
    } else {
        // empty region: softmax over all -1e30 -> uniform mean of v over all T
        for (int t = grp; t < NT; t += 8) {
            const float* vp = vb + (size_t)t * ND;
            const float4 va = *(const float4*)(vp + dlo);
            const float4 vc = *(const float4*)(vp + 32 + dlo);
            acc[0][0] += va.x; acc[0][1] += va.y; acc[0][2] += va.z; acc[0][3] += va.w;
            acc[0][4] += vc.x; acc[0][5] += vc.y; acc[0][6] += vc.z; acc[0][7] += vc.w;
        }
        #pragma unroll
        for (int p = 1; p < 4; ++p)
            #pragma unroll
            for (int i = 0; i < 8; ++i) acc[p][i] = acc[0][i];
        // butterfly below sums 8 groups: pre-divide so l totals NT
        l4[0] = l4[1] = l4[2] = l4[3] = (float)NT * 0.125f;
    }

    // butterfly-reduce the 8 token-groups (bits 3..5); all lanes end with totals
    #pragma unroll
    for (int m = 8; m <= 32; m <<= 1) {
        #pragma unroll
        for (int p = 0; p < 4; ++p) {
            l4[p] += __shfl_xor(l4[p], m);
            #pragma unroll
            for (int i = 0; i < 8; ++i) acc[p][i] += __shfl_xor(acc[p][i], m);
        }
    }

    // groups 0..3 write pool p0+grp; non-temporal (out never re-read)
    #pragma unroll
    for (int p = 0; p < 4; ++p) {
        if (grp == p) {
            const float inv = 1.f / l4[p];
            float* op = out + (bh * NP + p0 + p) * ND;
            const vfloat4 o0 = {acc[p][0] * inv, acc[p][1] * inv,
                                acc[p][2] * inv, acc[p][3] * inv};
            const vfloat4 o1 = {acc[p][4] * inv, acc[p][5] * inv,
                                acc[p][6] * inv, acc[p][7] * inv};
            __builtin_nontemporal_store(o0, (vfloat4*)(op + dlo));
            __builtin_nontemporal_store(o1, (vfloat4*)(op + 32 + dlo));
        }
    }
}

extern "C" void kernel_launch(void* const* d_in, const int* in_sizes, int n_in,
                              void* d_out, int out_size, void* d_ws, size_t ws_size,
                              hipStream_t stream) {
    (void)in_sizes; (void)n_in; (void)d_ws; (void)ws_size; (void)out_size;
    const float* q       = (const float*)d_in[0];
    const float* k       = (const float*)d_in[1];
    const float* v       = (const float*)d_in[2];
    const int*   regions = (const int*)d_in[3];
    // d_in[4] t_mask, d_in[5] n_mask all-true; d_in[6] max_n == 64
    float* out = (float*)d_out;

    lca_kernel<<<dim3(NB * NH * (NREG / 4)), 256, 0, stream>>>(q, k, v, regions, out);
}